// Round 1
// baseline (458.424 us; speedup 1.0000x reference)
//
#include <hip/hip_runtime.h>

#define N_ROWS 4096
#define DIM1   512
#define DIM2   128
#define BN     256

typedef __bf16 bf16_t;
typedef bf16_t bf16x8 __attribute__((ext_vector_type(8)));
typedef bf16_t bf16x4 __attribute__((ext_vector_type(4)));
typedef float  f32x4  __attribute__((ext_vector_type(4)));

// Y[n,k] = sum_{i,j} X[n,i] W[k,i,j] X[n,j]
// Computed as: for each i-tile: acc[n,i] = sum_j X[n,j](bf16) * W[k,i,j](bf16)  [MFMA, j = K-dim]
//              then ypart[n] += acc[n,i] * X[n,i] (fp32)                        [fused epilogue]
// Block: 512 thr (8 waves), BN=256 rows, one k per block. A-frags (X along j) in regs.
__global__ __launch_bounds__(512, 2)
void tensor_reduction_kernel(const float* __restrict__ X,
                             const float* __restrict__ W,
                             float* __restrict__ Y)
{
    const int bid = blockIdx.x;
    // XCD swizzle: same-k blocks consecutive on one XCD so W_k stays in its L2.
    const int xcd = bid & 7;
    const int rr_ = bid >> 3;                 // 0..255
    const int kk  = xcd + 8 * (rr_ >> 4);     // 0..127
    const int nb  = (rr_ & 15) * BN;          // row-block base

    const int tid = threadIdx.x;
    const int wv  = tid >> 6;                 // wave 0..7 -> rows wv*32..wv*32+31
    const int ln  = tid & 63;
    const int lg  = ln >> 4;                  // 0..3
    const int lr  = ln & 15;                  // 0..15

    __shared__ __align__(16) bf16_t Xs[BN * 64];      // 32 KB staging (rows of 128 B, XOR-swizzled)
    __shared__ __align__(16) bf16_t Ws[2][64 * 64];   // 2 x 8 KB W double-buffer

    // ---------------- Load A fragments: X[nb..nb+255][0..511] -> bf16 regs ----------------
    // afrag[m][f]: rows wv*32+m*16+lr, j = f*32 + lg*8 + e  (MFMA A layout: row=l&15, k=(l>>4)*8+e)
    bf16x8 afrag[2][16];
    {
        const int srow = tid >> 4;            // 0..31
        const int sj4  = (tid & 15) * 4;      // 0..60
        #pragma unroll
        for (int c = 0; c < 8; ++c) {         // 64-column chunks
            #pragma unroll
            for (int p = 0; p < 8; ++p) {
                const int row = p * 32 + srow;
                float4 v = *reinterpret_cast<const float4*>(
                    X + (size_t)(nb + row) * DIM1 + c * 64 + sj4);
                bf16x4 h = { (bf16_t)v.x, (bf16_t)v.y, (bf16_t)v.z, (bf16_t)v.w };
                const int byte = row * 128 + ((sj4 * 2) ^ ((row & 7) << 4));
                *reinterpret_cast<bf16x4*>((char*)Xs + byte) = h;
            }
            __syncthreads();
            #pragma unroll
            for (int m = 0; m < 2; ++m) {
                #pragma unroll
                for (int ks = 0; ks < 2; ++ks) {
                    const int row  = wv * 32 + m * 16 + lr;
                    const int byte = row * 128 + ((ks * 64 + lg * 16) ^ ((row & 7) << 4));
                    afrag[m][2 * c + ks] =
                        *reinterpret_cast<const bf16x8*>((const char*)Xs + byte);
                }
            }
            __syncthreads();
        }
    }

    const float* Wk  = W + (size_t)kk * DIM1 * DIM1;
    const int irow = tid >> 3;        // 0..63  (i row within LDS tile)
    const int j8   = (tid & 7) * 8;   // 0..56  (j col within LDS tile)

    float ypart[2][4] = {{0.f,0.f,0.f,0.f},{0.f,0.f,0.f,0.f}};

    // stage tile (it=0, jc=0) into Ws[0]
    {
        const float* src = Wk + (size_t)irow * DIM1 + j8;
        float4 u0 = *reinterpret_cast<const float4*>(src);
        float4 u1 = *reinterpret_cast<const float4*>(src + 4);
        bf16x8 h = { (bf16_t)u0.x,(bf16_t)u0.y,(bf16_t)u0.z,(bf16_t)u0.w,
                     (bf16_t)u1.x,(bf16_t)u1.y,(bf16_t)u1.z,(bf16_t)u1.w };
        const int byte = irow * 128 + ((j8 * 2) ^ ((irow & 7) << 4));
        *reinterpret_cast<bf16x8*>((char*)Ws[0] + byte) = h;
    }
    __syncthreads();

    for (int it = 0; it < 8; ++it) {          // i-tiles of 64 (acc N-dim)
        f32x4 acc[2][4] = {};
        #pragma unroll
        for (int jc = 0; jc < 8; ++jc) {      // j-chunks of 64 (contraction)
            const int tI  = it * 8 + jc;      // linear tile index 0..63
            const int cur = tI & 1;
            float4 u0, u1;
            const bool pf = (tI < 63);
            if (pf) {                          // issue next tile's global loads early (T14-lite)
                const int nit = (tI + 1) >> 3, njc = (tI + 1) & 7;
                const float* src = Wk + (size_t)(nit * 64 + irow) * DIM1 + njc * 64 + j8;
                u0 = *reinterpret_cast<const float4*>(src);
                u1 = *reinterpret_cast<const float4*>(src + 4);
            }
            // compute on Ws[cur]: B-frag col=i (l&15), k=j consecutive (l>>4)*8+e
            #pragma unroll
            for (int ks = 0; ks < 2; ++ks) {
                bf16x8 bfr[4];
                #pragma unroll
                for (int f = 0; f < 4; ++f) {
                    const int ir   = f * 16 + lr;
                    const int byte = ir * 128 + ((ks * 64 + lg * 16) ^ ((ir & 7) << 4));
                    bfr[f] = *reinterpret_cast<const bf16x8*>((const char*)Ws[cur] + byte);
                }
                #pragma unroll
                for (int m = 0; m < 2; ++m)
                    #pragma unroll
                    for (int f = 0; f < 4; ++f)
                        acc[m][f] = __builtin_amdgcn_mfma_f32_16x16x32_bf16(
                            afrag[m][2 * jc + ks], bfr[f], acc[m][f], 0, 0, 0);
            }
            if (pf) {                          // convert + LDS-write after compute
                bf16x8 h = { (bf16_t)u0.x,(bf16_t)u0.y,(bf16_t)u0.z,(bf16_t)u0.w,
                             (bf16_t)u1.x,(bf16_t)u1.y,(bf16_t)u1.z,(bf16_t)u1.w };
                const int byte = irow * 128 + ((j8 * 2) ^ ((irow & 7) << 4));
                *reinterpret_cast<bf16x8*>((char*)Ws[cur ^ 1] + byte) = h;
            }
            __syncthreads();
        }
        // fused epilogue for this i-tile: ypart[n] += acc[n][i] * X[n][i]
        // C/D layout: col=l&15 (=i), row=(l>>4)*4+q (=n)
        #pragma unroll
        for (int m = 0; m < 2; ++m) {
            #pragma unroll
            for (int f = 0; f < 4; ++f) {
                const int col = it * 64 + f * 16 + lr;
                #pragma unroll
                for (int q = 0; q < 4; ++q) {
                    const int grow = nb + wv * 32 + m * 16 + lg * 4 + q;
                    ypart[m][q] += acc[m][f][q] * X[(size_t)grow * DIM1 + col];
                }
            }
        }
    }

    // reduce the 16 column-lanes (masks 1,2,4,8 stay within each 16-lane group), store
    #pragma unroll
    for (int m = 0; m < 2; ++m) {
        #pragma unroll
        for (int q = 0; q < 4; ++q) {
            float v = ypart[m][q];
            v += __shfl_xor(v, 1, 64);
            v += __shfl_xor(v, 2, 64);
            v += __shfl_xor(v, 4, 64);
            v += __shfl_xor(v, 8, 64);
            if (lr == 0) {
                const int grow = nb + wv * 32 + m * 16 + lg * 4 + q;
                Y[(size_t)grow * DIM2 + kk] = v;
            }
        }
    }
}

extern "C" void kernel_launch(void* const* d_in, const int* in_sizes, int n_in,
                              void* d_out, int out_size, void* d_ws, size_t ws_size,
                              hipStream_t stream)
{
    const float* X = (const float*)d_in[0];   // [4096, 512] fp32
    const float* W = (const float*)d_in[1];   // [128, 512, 512] fp32
    float* Y = (float*)d_out;                 // [4096, 128] fp32
    dim3 grid(2048), block(512);
    tensor_reduction_kernel<<<grid, block, 0, stream>>>(X, W, Y);
}